// Round 1
// baseline (1090.057 us; speedup 1.0000x reference)
//
#include <hip/hip_runtime.h>
#include <math.h>
#include <stdint.h>

#define DI __device__ __forceinline__

// ---------------------------------------------------------------- helpers
DI float elu_f(float v) { return v > 0.f ? v : expm1f(v); }

DI float loadA(const float* __restrict__ A0, int K0,
               const float* __restrict__ A1, int K1,
               int row, int col) {
  // concat([A0, A1], axis=1) element (row, col); caller guarantees col < K0+K1
  if (col < K0) return A0[row * K0 + col];
  return A1[row * K1 + (col - K0)];
}

// ---------------------------------------------------------------- threefry2x32 (JAX-compatible, 20 rounds)
DI void threefry2x32(uint32_t k0, uint32_t k1, uint32_t& x0, uint32_t& x1) {
  uint32_t ks0 = k0, ks1 = k1, ks2 = k0 ^ k1 ^ 0x1BD11BDAu;
  x0 += ks0; x1 += ks1;
#define TFR(r) { x0 += x1; x1 = (x1 << r) | (x1 >> (32 - r)); x1 ^= x0; }
  TFR(13) TFR(15) TFR(26) TFR(6)   x0 += ks1; x1 += ks2 + 1u;
  TFR(17) TFR(29) TFR(16) TFR(24)  x0 += ks2; x1 += ks0 + 2u;
  TFR(13) TFR(15) TFR(26) TFR(6)   x0 += ks0; x1 += ks1 + 3u;
  TFR(17) TFR(29) TFR(16) TFR(24)  x0 += ks1; x1 += ks2 + 4u;
  TFR(13) TFR(15) TFR(26) TFR(6)   x0 += ks2; x1 += ks0 + 5u;
#undef TFR
}

// Giles erfinv (f32 coeffs) refined with 2 Newton steps in double.
DI float erfinv_refined(float uf) {
  double x = (double)uf;
  double w = -log((1.0 - x) * (1.0 + x));
  double p;
  if (w < 5.0) {
    w -= 2.5;
    p = 2.81022636e-08;
    p = fma(p, w, 3.43273939e-07);
    p = fma(p, w, -3.5233877e-06);
    p = fma(p, w, -4.39150654e-06);
    p = fma(p, w, 0.00021858087);
    p = fma(p, w, -0.00125372503);
    p = fma(p, w, -0.00417768164);
    p = fma(p, w, 0.246640727);
    p = fma(p, w, 1.50140941);
  } else {
    w = sqrt(w) - 3.0;
    p = -0.000200214257;
    p = fma(p, w, 0.000100950558);
    p = fma(p, w, 0.00134934322);
    p = fma(p, w, -0.00367342844);
    p = fma(p, w, 0.00573950773);
    p = fma(p, w, -0.0076224613);
    p = fma(p, w, 0.00943887047);
    p = fma(p, w, 1.00167406);
    p = fma(p, w, 2.83297682);
  }
  double r = p * x;
  const double kk = 0.886226925452758013649;  // sqrt(pi)/2
  r -= (erf(r) - x) * kk * exp(r * r);
  r -= (erf(r) - x) * kk * exp(r * r);
  return (float)r;
}

// z = mu + eps * exp(0.5*logvar); eps == jax.random.normal(key(42), (2048,32))
// with the partitionable threefry scheme: bits[j] = xor(threefry((0,42),(0,j))).
__global__ __launch_bounds__(256)
void z_eps_kernel(const float* __restrict__ mu, const float* __restrict__ lv,
                  float* __restrict__ z, int n) {
  int j = blockIdx.x * blockDim.x + threadIdx.x;
  if (j >= n) return;
  uint32_t x0 = 0u, x1 = (uint32_t)j;
  threefry2x32(0u, 42u, x0, x1);
  uint32_t bits = x0 ^ x1;
  float f = __uint_as_float((bits >> 9) | 0x3F800000u) - 1.0f;  // [0,1)
  const float lo = -0.99999994039535522461f;                    // nextafter(-1,0)
  float u = fmaf(f, 2.0f, lo);    // (hi-lo) rounds to exactly 2.0f; fma result exact
  u = fmaxf(u, lo);
  float eps = 1.41421356237f * erfinv_refined(u);  // f32(sqrt(2)) * f32 erfinv
  z[j] = fmaf(eps, expf(0.5f * lv[j]), mu[j]);
}

// ---------------------------------------------------------------- generic linear: C = act(concat(A0,A1) @ W^T + b)
// W is [N, K] row-major (out_features, in_features). BM=32 fixed, 256 threads.
template <int BN, bool ELU>
__global__ __launch_bounds__(256)
void linear_kernel(const float* __restrict__ A0, int K0,
                   const float* __restrict__ A1, int K1,
                   const float* __restrict__ W, const float* __restrict__ bias,
                   float* __restrict__ C, int N) {
  constexpr int BM = 32, BK = 16;
  constexpr int TM = 2, TN = BN / 16;
  const int K = K0 + K1;
  __shared__ float As[BK][BM + 2];
  __shared__ float Ws[BK][BN + 4];
  const int tid = threadIdx.x;
  const int tx = tid & 15, ty = tid >> 4;
  const int m0 = blockIdx.y * BM, n0 = blockIdx.x * BN;
  float acc[TM][TN] = {};
  for (int k0 = 0; k0 < K; k0 += BK) {
#pragma unroll
    for (int idx = tid; idx < BM * BK; idx += 256) {
      int m = idx >> 4, k = idx & 15;
      int col = k0 + k;
      As[k][m] = (col < K) ? loadA(A0, K0, A1, K1, m0 + m, col) : 0.f;
    }
#pragma unroll
    for (int idx = tid; idx < BN * BK; idx += 256) {
      int n = idx >> 4, k = idx & 15;
      int col = k0 + k, nn = n0 + n;
      Ws[k][n] = (col < K && nn < N) ? W[(size_t)nn * K + col] : 0.f;
    }
    __syncthreads();
#pragma unroll
    for (int kk = 0; kk < BK; kk++) {
      float a[TM], wv[TN];
#pragma unroll
      for (int i = 0; i < TM; i++) a[i] = As[kk][ty * TM + i];
#pragma unroll
      for (int j = 0; j < TN; j++) wv[j] = Ws[kk][tx * TN + j];
#pragma unroll
      for (int i = 0; i < TM; i++)
#pragma unroll
        for (int j = 0; j < TN; j++) acc[i][j] = fmaf(a[i], wv[j], acc[i][j]);
    }
    __syncthreads();
  }
#pragma unroll
  for (int i = 0; i < TM; i++) {
    int m = m0 + ty * TM + i;
#pragma unroll
    for (int j = 0; j < TN; j++) {
      int n = n0 + tx * TN + j;
      if (n < N) {
        float v = acc[i][j] + bias[n];
        if (ELU) v = elu_f(v);
        C[(size_t)m * N + n] = v;
      }
    }
  }
}

// ---------------------------------------------------------------- gate layer 2 + softmax: coeff = softmax(gb @ g2w^T + g2b)
__global__ __launch_bounds__(256)
void gate_softmax_kernel(const float* __restrict__ gb, const float* __restrict__ g2w,
                         const float* __restrict__ g2b, float* __restrict__ coeff) {
  __shared__ float Wl[8][64];
  __shared__ float Gs[32][65];
  __shared__ float lg[32][8];
  const int tid = threadIdx.x;
  const int r0 = blockIdx.x * 32;
  for (int idx = tid; idx < 512; idx += 256) Wl[idx >> 6][idx & 63] = g2w[idx];
  for (int idx = tid; idx < 32 * 64; idx += 256) {
    int r = idx >> 6, k = idx & 63;
    Gs[r][k] = gb[(size_t)(r0 + r) * 64 + k];
  }
  __syncthreads();
  const int r = tid >> 3, e = tid & 7;
  float acc = g2b[e];
#pragma unroll
  for (int k = 0; k < 64; k++) acc = fmaf(Gs[r][k], Wl[e][k], acc);
  lg[r][e] = acc;
  __syncthreads();
  float mx = lg[r][0];
#pragma unroll
  for (int t = 1; t < 8; t++) mx = fmaxf(mx, lg[r][t]);
  float s = 0.f;
#pragma unroll
  for (int t = 0; t < 8; t++) s += expf(lg[r][t] - mx);
  coeff[(size_t)(r0 + r) * 8 + e] = expf(acc - mx) / s;
}

// ---------------------------------------------------------------- MoE decoder layer:
// C[b,o] = act( sum_e coeff[b,e] * ( concat(A0,A1)[b,:] @ W[e,:,o] + bE[e,o] ) )
// W is [8, K, N] row-major. Full-K A panel staged in LDS once, experts loop over it.
template <bool ELU>
__global__ __launch_bounds__(256)
void moe_kernel(const float* __restrict__ A0, int K0,
                const float* __restrict__ A1, int K1,
                const float* __restrict__ W, const float* __restrict__ bE,
                const float* __restrict__ coeff, float* __restrict__ C, int N) {
  constexpr int BM = 32, BN = 64, BK = 16, TM = 2, TN = 4, APS = 305;
  const int K = K0 + K1;  // <= 299
  __shared__ float Ap[BM * APS];
  __shared__ float Ws[BK][BN + 4];
  __shared__ float cfs[BM][8];
  const int tid = threadIdx.x;
  const int tx = tid & 15, ty = tid >> 4;
  const int m0 = blockIdx.y * BM, n0 = blockIdx.x * BN;

  {  // stage A panel (zero-pad cols K..APS-1)
    const int w4 = tid >> 6, lane = tid & 63;
    for (int m = w4; m < BM; m += 4) {
      const int row = m0 + m;
      for (int cidx = lane; cidx < APS; cidx += 64) {
        float v = 0.f;
        if (cidx < K) v = loadA(A0, K0, A1, K1, row, cidx);
        Ap[m * APS + cidx] = v;
      }
    }
  }
  for (int idx = tid; idx < BM * 8; idx += 256)
    cfs[idx >> 3][idx & 7] = coeff[(size_t)(m0 + (idx >> 3)) * 8 + (idx & 7)];
  __syncthreads();

  float accF[TM][TN] = {};
  for (int e = 0; e < 8; e++) {
    float acc[TM][TN] = {};
    for (int k0 = 0; k0 < K; k0 += BK) {
#pragma unroll
      for (int idx = tid; idx < BN * BK; idx += 256) {
        int n = idx & 63, k = idx >> 6;
        int col = k0 + k, nn = n0 + n;
        Ws[k][n] = (col < K && nn < N) ? W[((size_t)e * K + col) * N + nn] : 0.f;
      }
      __syncthreads();
#pragma unroll
      for (int kk = 0; kk < BK; kk++) {
        float a[TM], wv[TN];
#pragma unroll
        for (int i = 0; i < TM; i++) a[i] = Ap[(ty * TM + i) * APS + k0 + kk];
#pragma unroll
        for (int j = 0; j < TN; j++) wv[j] = Ws[kk][tx * TN + j];
#pragma unroll
        for (int i = 0; i < TM; i++)
#pragma unroll
          for (int j = 0; j < TN; j++) acc[i][j] = fmaf(a[i], wv[j], acc[i][j]);
      }
      __syncthreads();
    }
#pragma unroll
    for (int i = 0; i < TM; i++) {
      float ce = cfs[ty * TM + i][e];
#pragma unroll
      for (int j = 0; j < TN; j++) {
        int n = n0 + tx * TN + j;
        float bv = (n < N) ? bE[(size_t)e * N + n] : 0.f;
        accF[i][j] = fmaf(ce, acc[i][j] + bv, accF[i][j]);
      }
    }
  }
#pragma unroll
  for (int i = 0; i < TM; i++) {
    int m = m0 + ty * TM + i;
#pragma unroll
    for (int j = 0; j < TN; j++) {
      int n = n0 + tx * TN + j;
      if (n < N) {
        float v = accF[i][j];
        if (ELU) v = elu_f(v);
        C[(size_t)m * N + n] = v;
      }
    }
  }
}

// ---------------------------------------------------------------- launch
extern "C" void kernel_launch(void* const* d_in, const int* in_sizes, int n_in,
                              void* d_out, int out_size, void* d_ws, size_t ws_size,
                              hipStream_t stream) {
  (void)in_sizes; (void)n_in; (void)out_size; (void)ws_size;
  const float* x    = (const float*)d_in[0];
  const float* c    = (const float*)d_in[1];
  const float* fc1w = (const float*)d_in[2];
  const float* fc1b = (const float*)d_in[3];
  const float* fc2w = (const float*)d_in[4];
  const float* fc2b = (const float*)d_in[5];
  const float* muw  = (const float*)d_in[6];
  const float* mub  = (const float*)d_in[7];
  const float* lvw  = (const float*)d_in[8];
  const float* lvb  = (const float*)d_in[9];
  const float* g0w  = (const float*)d_in[10];
  const float* g0b  = (const float*)d_in[11];
  const float* g1w  = (const float*)d_in[12];
  const float* g1b  = (const float*)d_in[13];
  const float* g2w  = (const float*)d_in[14];
  const float* g2b  = (const float*)d_in[15];
  const float* w0   = (const float*)d_in[16];
  const float* b0   = (const float*)d_in[17];
  const float* w1   = (const float*)d_in[18];
  const float* b1   = (const float*)d_in[19];
  const float* w2   = (const float*)d_in[20];
  const float* b2   = (const float*)d_in[21];

  float* out   = (float*)d_out;
  float* outY  = out;                 // [2048,267]
  float* outMu = out + 2048 * 267;    // [2048,32]
  float* outLv = outMu + 2048 * 32;   // [2048,32]

  float* ws  = (float*)d_ws;
  float* h1  = ws;                    // 2048*256
  float* h2  = ws + 524288;           // 2048*256
  float* z   = ws + 1048576;          // 2048*32
  float* ga  = ws + 1114112;          // 2048*64
  float* gb  = ws + 1245184;          // 2048*64
  float* cf  = ws + 1376256;          // 2048*8
  float* dh0 = h1;                    // reuse (h1 dead after fc2)
  float* dh1 = h2;                    // reuse (h2 dead after mu/lv)

  dim3 blk(256);
  // encoder
  linear_kernel<64, true ><<<dim3(4, 64), blk, 0, stream>>>(x, 267, c,   267, fc1w, fc1b, h1,    256);
  linear_kernel<64, true ><<<dim3(4, 64), blk, 0, stream>>>(x, 267, h1,  256, fc2w, fc2b, h2,    256);
  linear_kernel<32, false><<<dim3(1, 64), blk, 0, stream>>>(x, 267, h2,  256, muw,  mub,  outMu, 32);
  linear_kernel<32, false><<<dim3(1, 64), blk, 0, stream>>>(x, 267, h2,  256, lvw,  lvb,  outLv, 32);
  // reparameterize
  z_eps_kernel<<<dim3(256), blk, 0, stream>>>(outMu, outLv, z, 2048 * 32);
  // gate
  linear_kernel<64, true ><<<dim3(1, 64), blk, 0, stream>>>(z, 32, c,       267, g0w, g0b, ga, 64);
  linear_kernel<64, true ><<<dim3(1, 64), blk, 0, stream>>>(ga, 64, nullptr, 0,  g1w, g1b, gb, 64);
  gate_softmax_kernel<<<dim3(64), blk, 0, stream>>>(gb, g2w, g2b, cf);
  // mixture-of-experts decoder
  moe_kernel<true ><<<dim3(4, 64), blk, 0, stream>>>(z, 32, c,   267, w0, b0, cf, dh0,  256);
  moe_kernel<true ><<<dim3(4, 64), blk, 0, stream>>>(z, 32, dh0, 256, w1, b1, cf, dh1,  256);
  moe_kernel<false><<<dim3(5, 64), blk, 0, stream>>>(z, 32, dh1, 256, w2, b2, cf, outY, 267);
}

// Round 2
// 302.114 us; speedup vs baseline: 3.6081x; 3.6081x over previous
//
#include <hip/hip_runtime.h>
#include <math.h>
#include <stdint.h>

#define DI __device__ __forceinline__

typedef __attribute__((ext_vector_type(8))) short bf16x8;
typedef __attribute__((ext_vector_type(4))) float f32x4;
typedef __attribute__((ext_vector_type(4))) int i32x4;

DI float elu_f(float v) { return v > 0.f ? v : expm1f(v); }

DI unsigned short f2bf(float f) {  // fp32 -> bf16 round-to-nearest-even
  uint32_t u = __float_as_uint(f);
  uint32_t r = (u + 0x7FFFu + ((u >> 16) & 1u)) >> 16;
  return (unsigned short)r;
}

DI float loadA_cc(const float* __restrict__ A0, int K0,
                  const float* __restrict__ A1, int K1,
                  int row, int col) {
  if (col < K0) return A0[row * K0 + col];
  return A1[row * K1 + (col - K0)];
}

// ---------------------------------------------------------------- threefry2x32 (JAX-compatible, 20 rounds)
DI void threefry2x32(uint32_t k0, uint32_t k1, uint32_t& x0, uint32_t& x1) {
  uint32_t ks0 = k0, ks1 = k1, ks2 = k0 ^ k1 ^ 0x1BD11BDAu;
  x0 += ks0; x1 += ks1;
#define TFR(r) { x0 += x1; x1 = (x1 << r) | (x1 >> (32 - r)); x1 ^= x0; }
  TFR(13) TFR(15) TFR(26) TFR(6)   x0 += ks1; x1 += ks2 + 1u;
  TFR(17) TFR(29) TFR(16) TFR(24)  x0 += ks2; x1 += ks0 + 2u;
  TFR(13) TFR(15) TFR(26) TFR(6)   x0 += ks0; x1 += ks1 + 3u;
  TFR(17) TFR(29) TFR(16) TFR(24)  x0 += ks1; x1 += ks2 + 4u;
  TFR(13) TFR(15) TFR(26) TFR(6)   x0 += ks2; x1 += ks0 + 5u;
#undef TFR
}

DI float erfinv_refined(float uf) {
  double x = (double)uf;
  double w = -log((1.0 - x) * (1.0 + x));
  double p;
  if (w < 5.0) {
    w -= 2.5;
    p = 2.81022636e-08;
    p = fma(p, w, 3.43273939e-07);
    p = fma(p, w, -3.5233877e-06);
    p = fma(p, w, -4.39150654e-06);
    p = fma(p, w, 0.00021858087);
    p = fma(p, w, -0.00125372503);
    p = fma(p, w, -0.00417768164);
    p = fma(p, w, 0.246640727);
    p = fma(p, w, 1.50140941);
  } else {
    w = sqrt(w) - 3.0;
    p = -0.000200214257;
    p = fma(p, w, 0.000100950558);
    p = fma(p, w, 0.00134934322);
    p = fma(p, w, -0.00367342844);
    p = fma(p, w, 0.00573950773);
    p = fma(p, w, -0.0076224613);
    p = fma(p, w, 0.00943887047);
    p = fma(p, w, 1.00167406);
    p = fma(p, w, 2.83297682);
  }
  double r = p * x;
  const double kk = 0.886226925452758013649;  // sqrt(pi)/2
  r -= (erf(r) - x) * kk * exp(r * r);
  r -= (erf(r) - x) * kk * exp(r * r);
  return (float)r;
}

// z = mu + eps * exp(0.5*logvar); writes bf16 z into A0/A1/A2 cols [0,32)
__global__ __launch_bounds__(256)
void z_eps_kernel(const float* __restrict__ mu, const float* __restrict__ lv,
                  unsigned short* __restrict__ A0, unsigned short* __restrict__ A1,
                  unsigned short* __restrict__ A2) {
  int j = blockIdx.x * blockDim.x + threadIdx.x;
  if (j >= 2048 * 32) return;
  uint32_t x0 = 0u, x1 = (uint32_t)j;
  threefry2x32(0u, 42u, x0, x1);
  uint32_t bits = x0 ^ x1;
  float f = __uint_as_float((bits >> 9) | 0x3F800000u) - 1.0f;  // [0,1)
  const float lo = -0.99999994039535522461f;                    // nextafter(-1,0)
  float u = fmaf(f, 2.0f, lo);
  u = fmaxf(u, lo);
  float eps = 1.41421356237f * erfinv_refined(u);
  float zv = fmaf(eps, expf(0.5f * lv[j]), mu[j]);
  unsigned short zb = f2bf(zv);
  int b = j >> 5, t = j & 31;
  A0[(size_t)b * 320 + t] = zb;
  A1[(size_t)b * 288 + t] = zb;
  A2[(size_t)b * 288 + t] = zb;
}

// ---------------------------------------------------------------- prep: pack A matrices (bf16, padded)
__global__ __launch_bounds__(256)
void prep_rows(const float* __restrict__ x, const float* __restrict__ c,
               unsigned short* __restrict__ Ax, unsigned short* __restrict__ Axh,
               unsigned short* __restrict__ Axh2, unsigned short* __restrict__ A0) {
  int b = blockIdx.x, tid = threadIdx.x;
  const float* xr = x + (size_t)b * 267;
  const float* cr = c + (size_t)b * 267;
  unsigned short* axr = Ax + (size_t)b * 544;
  for (int k = tid; k < 544; k += 256) {
    float v = (k < 267) ? xr[k] : ((k < 534) ? cr[k - 267] : 0.f);
    axr[k] = f2bf(v);
  }
  unsigned short* ahr = Axh + (size_t)b * 544;
  unsigned short* ah2 = Axh2 + (size_t)b * 544;
  for (int k = tid; k < 267; k += 256) { unsigned short v = f2bf(xr[k]); ahr[k] = v; ah2[k] = v; }
  for (int k = 523 + tid; k < 544; k += 256) { ahr[k] = 0; ah2[k] = 0; }
  unsigned short* a0r = A0 + (size_t)b * 320;
  for (int k = tid; k < 288; k += 256)
    a0r[32 + k] = (k < 267) ? f2bf(cr[k]) : (unsigned short)0;
}

// prep: convert row-major [N,K] fp32 weights -> [N,Kp] bf16 (already B^T layout)
__global__ __launch_bounds__(256)
void prep_weights(const float* __restrict__ fc1w, const float* __restrict__ fc2w,
                  const float* __restrict__ muw, const float* __restrict__ lvw,
                  const float* __restrict__ g0w,
                  unsigned short* __restrict__ fc1t, unsigned short* __restrict__ fc2t,
                  unsigned short* __restrict__ mlvt, unsigned short* __restrict__ g0t) {
  int r = blockIdx.x, tid = threadIdx.x;
  const float* src; unsigned short* dst; int Ks, Kp;
  if (r < 256)      { src = fc1w + (size_t)r * 534; dst = fc1t + (size_t)r * 544; Ks = 534; Kp = 544; }
  else if (r < 512) { int n = r - 256; src = fc2w + (size_t)n * 523; dst = fc2t + (size_t)n * 544; Ks = 523; Kp = 544; }
  else if (r < 576) { int n = r - 512; src = (n < 32) ? (muw + (size_t)n * 523) : (lvw + (size_t)(n - 32) * 523);
                      dst = mlvt + (size_t)n * 544; Ks = 523; Kp = 544; }
  else              { int n = r - 576; src = g0w + (size_t)n * 299; dst = g0t + (size_t)n * 320; Ks = 299; Kp = 320; }
  for (int k = tid; k < Kp; k += 256) dst[k] = (k < Ks) ? f2bf(src[k]) : (unsigned short)0;
}

// prep: transpose-convert expert weights [E,K,N] fp32 -> [E,N,Kp] bf16
__global__ __launch_bounds__(256)
void prep_wT(const float* __restrict__ w0, const float* __restrict__ w1,
             const float* __restrict__ w2,
             unsigned short* __restrict__ w0b, unsigned short* __restrict__ w1b,
             unsigned short* __restrict__ w2b) {
  int r = blockIdx.x, tid = threadIdx.x;
  if (r < 2048) {
    int e = r >> 8, n = r & 255;
    const float* s = w0 + (size_t)e * 299 * 256 + n;
    unsigned short* d = w0b + ((size_t)e * 256 + n) * 320;
    for (int k = tid; k < 320; k += 256) d[k] = (k < 299) ? f2bf(s[(size_t)k * 256]) : (unsigned short)0;
  } else if (r < 4096) {
    int e = (r - 2048) >> 8, n = (r - 2048) & 255;
    const float* s = w1 + (size_t)e * 288 * 256 + n;
    unsigned short* d = w1b + ((size_t)e * 256 + n) * 288;
    for (int k = tid; k < 288; k += 256) d[k] = f2bf(s[(size_t)k * 256]);
  } else {
    int rr = r - 4096; int e = rr / 267, n = rr % 267;
    const float* s = w2 + (size_t)e * 288 * 267 + n;
    unsigned short* d = w2b + ((size_t)e * 267 + n) * 288;
    for (int k = tid; k < 288; k += 256) d[k] = f2bf(s[(size_t)k * 267]);
  }
}

// ---------------------------------------------------------------- unified bf16 MFMA GEMM
// C = [act]( A[M x lda] @ Bt^T + bias ), Bt stored [ (E x) N x ldb ] bf16 (k-contiguous).
// EXPERTS: loop 8 experts, fold fp32: accF += coeff[row,e]*(acc_e + bias[e,n]).
// SPLITK: gridDim.z = 4 K-chunks, write raw fp32 partials P[z][2048][N].
// Block 64x64, 256 thr = 4 waves of 32x32 (2x2 frags of 16x16x32).
template <int KT, bool EXPERTS, bool SPLITK, bool ELU_ACT>
__global__ __launch_bounds__(256)
void mfma_gemm(const unsigned short* __restrict__ A, int lda,
               const unsigned short* __restrict__ Bt, int ldb, int N,
               const float* __restrict__ bias, const float* __restrict__ coeff,
               float* __restrict__ Cf, int ldc,
               unsigned short* __restrict__ Cb, int ldcb, int cb_off) {
  constexpr int LKA = KT * 32 + 8;   // +8 bf16 pad: row stride % 32 dwords = 4 -> 2-way conflicts
  constexpr int LKW = 40;            // 32 + 8 pad
  constexpr int NE = EXPERTS ? 8 : 1;
  __shared__ unsigned short As[64 * LKA];
  __shared__ unsigned short Ws[2][64 * LKW];
  __shared__ float bias_s[NE][64];
  __shared__ float cfs[EXPERTS ? 64 : 1][8];

  const int tid = threadIdx.x;
  const int m0 = blockIdx.x * 64, n0 = blockIdx.y * 64;
  const int lane = tid & 63, wid = tid >> 6;
  const int q = lane >> 4, l16 = lane & 15;
  const int wm = (wid >> 1) * 32, wn = (wid & 1) * 32;

  int t_begin = 0, t_end = KT;
  if (SPLITK) {
    constexpr int CH = (KT + 3) / 4;
    t_begin = blockIdx.z * CH;
    t_end = min(KT, t_begin + CH);
  }
  const int TPE = t_end - t_begin;
  const int TT = NE * TPE;

  {  // stage full-K A panel (16B chunks, coalesced)
    constexpr int CPR = KT * 4;
    for (int idx = tid; idx < 64 * CPR; idx += 256) {
      int m = idx / CPR, cch = idx % CPR;
      i32x4 v = *(const i32x4*)(A + (size_t)(m0 + m) * lda + cch * 8);
      *(i32x4*)(&As[m * LKA + cch * 8]) = v;
    }
  }
  if (!SPLITK) {
    for (int idx = tid; idx < NE * 64; idx += 256) {
      int e = idx >> 6, n = idx & 63;
      bias_s[e][n] = (n0 + n < N) ? bias[(size_t)e * N + n0 + n] : 0.f;
    }
  }
  if (EXPERTS) {
    for (int idx = tid; idx < 64 * 8; idx += 256)
      cfs[idx >> 3][idx & 7] = coeff[(size_t)(m0 + (idx >> 3)) * 8 + (idx & 7)];
  }

  const int sn = tid >> 2, skc = tid & 3;  // W staging: row n, 16B chunk
  auto loadW = [&](int tau) -> i32x4 {
    int e = EXPERTS ? (tau / KT) : 0;
    int t = EXPERTS ? (tau % KT) : (t_begin + tau);
    i32x4 zz = {0, 0, 0, 0};
    int gn = n0 + sn;
    if (gn >= N) return zz;
    return *(const i32x4*)(&Bt[((size_t)e * N + gn) * ldb + t * 32 + skc * 8]);
  };

  i32x4 wreg = loadW(0);
  *(i32x4*)(&Ws[0][sn * LKW + skc * 8]) = wreg;

  f32x4 acc[2][2] = {};
  f32x4 accF[2][2] = {};

  for (int tau = 0; tau < TT; ++tau) {
    __syncthreads();  // Ws[tau&1] ready
    if (tau + 1 < TT) wreg = loadW(tau + 1);
    const int t = EXPERTS ? (tau % KT) : (t_begin + tau);
    const int buf = tau & 1;
    bf16x8 af[2], bfr[2];
#pragma unroll
    for (int mi = 0; mi < 2; mi++)
      af[mi] = *(const bf16x8*)(&As[(wm + mi * 16 + l16) * LKA + t * 32 + q * 8]);
#pragma unroll
    for (int ni = 0; ni < 2; ni++)
      bfr[ni] = *(const bf16x8*)(&Ws[buf][(wn + ni * 16 + l16) * LKW + q * 8]);
#pragma unroll
    for (int mi = 0; mi < 2; mi++)
#pragma unroll
      for (int ni = 0; ni < 2; ni++)
        acc[mi][ni] = __builtin_amdgcn_mfma_f32_16x16x32_bf16(af[mi], bfr[ni], acc[mi][ni], 0, 0, 0);
    if (tau + 1 < TT) *(i32x4*)(&Ws[(tau + 1) & 1][sn * LKW + skc * 8]) = wreg;
    if constexpr (EXPERTS) {
      if ((tau % KT) == KT - 1) {  // expert boundary: exact fp32 fold
        int e = tau / KT;
#pragma unroll
        for (int mi = 0; mi < 2; mi++) {
#pragma unroll
          for (int r = 0; r < 4; r++) {
            float ce = cfs[wm + mi * 16 + q * 4 + r][e];
#pragma unroll
            for (int ni = 0; ni < 2; ni++) {
              float bv = bias_s[e][wn + ni * 16 + l16];
              accF[mi][ni][r] += ce * (acc[mi][ni][r] + bv);
              acc[mi][ni][r] = 0.f;
            }
          }
        }
      }
    }
  }

  if constexpr (!EXPERTS) {
#pragma unroll
    for (int mi = 0; mi < 2; mi++)
#pragma unroll
      for (int ni = 0; ni < 2; ni++) accF[mi][ni] = acc[mi][ni];
  }

#pragma unroll
  for (int mi = 0; mi < 2; mi++) {
#pragma unroll
    for (int r = 0; r < 4; r++) {
      int row = m0 + wm + mi * 16 + q * 4 + r;
#pragma unroll
      for (int ni = 0; ni < 2; ni++) {
        int cl = wn + ni * 16 + l16;
        int cg = n0 + cl;
        if (cg >= N) continue;
        float v = accF[mi][ni][r];
        if (!EXPERTS && !SPLITK) v += bias_s[0][cl];
        if constexpr (SPLITK) {
          Cf[((size_t)blockIdx.z * 2048 + row) * N + cg] = v;
        } else {
          if (ELU_ACT) v = elu_f(v);
          if (Cf) Cf[(size_t)row * ldc + cg] = v;
          if (Cb) Cb[(size_t)row * ldcb + cb_off + cg] = f2bf(v);
        }
      }
    }
  }
}

// ---------------------------------------------------------------- split-K reduces
__global__ __launch_bounds__(256)
void reduce_mulv(const float* __restrict__ P, const float* __restrict__ mub,
                 const float* __restrict__ lvb, float* __restrict__ outMu,
                 float* __restrict__ outLv) {
  int idx = blockIdx.x * 256 + threadIdx.x;
  if (idx >= 2048 * 64) return;
  int b = idx >> 6, n = idx & 63;
  float v = P[idx] + P[131072 + idx] + P[262144 + idx] + P[393216 + idx];
  if (n < 32) outMu[b * 32 + n] = v + mub[n];
  else        outLv[b * 32 + n - 32] = v + lvb[n - 32];
}

__global__ __launch_bounds__(256)
void reduce_g0(const float* __restrict__ P, const float* __restrict__ g0b,
               float* __restrict__ ga) {
  int idx = blockIdx.x * 256 + threadIdx.x;
  if (idx >= 2048 * 64) return;
  int n = idx & 63;
  float v = P[idx] + P[131072 + idx] + P[262144 + idx] + P[393216 + idx] + g0b[n];
  ga[idx] = elu_f(v);
}

// ---------------------------------------------------------------- small fp32 linear (g1) + gate softmax
template <int BN, bool ELU>
__global__ __launch_bounds__(256)
void linear_kernel(const float* __restrict__ A0, int K0,
                   const float* __restrict__ A1, int K1,
                   const float* __restrict__ W, const float* __restrict__ bias,
                   float* __restrict__ C, int N) {
  constexpr int BM = 32, BK = 16;
  constexpr int TM = 2, TN = BN / 16;
  const int K = K0 + K1;
  __shared__ float As[BK][BM + 2];
  __shared__ float Wsh[BK][BN + 4];
  const int tid = threadIdx.x;
  const int tx = tid & 15, ty = tid >> 4;
  const int m0 = blockIdx.y * BM, n0 = blockIdx.x * BN;
  float acc[TM][TN] = {};
  for (int k0 = 0; k0 < K; k0 += BK) {
    for (int idx = tid; idx < BM * BK; idx += 256) {
      int m = idx >> 4, k = idx & 15;
      int col = k0 + k;
      As[k][m] = (col < K) ? loadA_cc(A0, K0, A1, K1, m0 + m, col) : 0.f;
    }
    for (int idx = tid; idx < BN * BK; idx += 256) {
      int n = idx >> 4, k = idx & 15;
      int col = k0 + k, nn = n0 + n;
      Wsh[k][n] = (col < K && nn < N) ? W[(size_t)nn * K + col] : 0.f;
    }
    __syncthreads();
#pragma unroll
    for (int kk = 0; kk < BK; kk++) {
      float a[TM], wv[TN];
#pragma unroll
      for (int i = 0; i < TM; i++) a[i] = As[kk][ty * TM + i];
#pragma unroll
      for (int j = 0; j < TN; j++) wv[j] = Wsh[kk][tx * TN + j];
#pragma unroll
      for (int i = 0; i < TM; i++)
#pragma unroll
        for (int j = 0; j < TN; j++) acc[i][j] = fmaf(a[i], wv[j], acc[i][j]);
    }
    __syncthreads();
  }
#pragma unroll
  for (int i = 0; i < TM; i++) {
    int m = m0 + ty * TM + i;
#pragma unroll
    for (int j = 0; j < TN; j++) {
      int n = n0 + tx * TN + j;
      if (n < N) {
        float v = acc[i][j] + bias[n];
        if (ELU) v = elu_f(v);
        C[(size_t)m * N + n] = v;
      }
    }
  }
}

__global__ __launch_bounds__(256)
void gate_softmax_kernel(const float* __restrict__ gb, const float* __restrict__ g2w,
                         const float* __restrict__ g2b, float* __restrict__ coeff) {
  __shared__ float Wl[8][64];
  __shared__ float Gs[32][65];
  __shared__ float lg[32][8];
  const int tid = threadIdx.x;
  const int r0 = blockIdx.x * 32;
  for (int idx = tid; idx < 512; idx += 256) Wl[idx >> 6][idx & 63] = g2w[idx];
  for (int idx = tid; idx < 32 * 64; idx += 256) {
    int r = idx >> 6, k = idx & 63;
    Gs[r][k] = gb[(size_t)(r0 + r) * 64 + k];
  }
  __syncthreads();
  const int r = tid >> 3, e = tid & 7;
  float acc = g2b[e];
#pragma unroll
  for (int k = 0; k < 64; k++) acc = fmaf(Gs[r][k], Wl[e][k], acc);
  lg[r][e] = acc;
  __syncthreads();
  float mx = lg[r][0];
#pragma unroll
  for (int t = 1; t < 8; t++) mx = fmaxf(mx, lg[r][t]);
  float s = 0.f;
#pragma unroll
  for (int t = 0; t < 8; t++) s += expf(lg[r][t] - mx);
  coeff[(size_t)(r0 + r) * 8 + e] = expf(acc - mx) / s;
}

// ---------------------------------------------------------------- launch
extern "C" void kernel_launch(void* const* d_in, const int* in_sizes, int n_in,
                              void* d_out, int out_size, void* d_ws, size_t ws_size,
                              hipStream_t stream) {
  (void)in_sizes; (void)n_in; (void)out_size; (void)ws_size;
  const float* x    = (const float*)d_in[0];
  const float* c    = (const float*)d_in[1];
  const float* fc1w = (const float*)d_in[2];
  const float* fc1b = (const float*)d_in[3];
  const float* fc2w = (const float*)d_in[4];
  const float* fc2b = (const float*)d_in[5];
  const float* muw  = (const float*)d_in[6];
  const float* mub  = (const float*)d_in[7];
  const float* lvw  = (const float*)d_in[8];
  const float* lvb  = (const float*)d_in[9];
  const float* g0w  = (const float*)d_in[10];
  const float* g0b  = (const float*)d_in[11];
  const float* g1w  = (const float*)d_in[12];
  const float* g1b  = (const float*)d_in[13];
  const float* g2w  = (const float*)d_in[14];
  const float* g2b  = (const float*)d_in[15];
  const float* w0   = (const float*)d_in[16];
  const float* b0   = (const float*)d_in[17];
  const float* w1   = (const float*)d_in[18];
  const float* b1   = (const float*)d_in[19];
  const float* w2   = (const float*)d_in[20];
  const float* b2   = (const float*)d_in[21];

  float* out   = (float*)d_out;
  float* outY  = out;                 // [2048,267]
  float* outMu = out + 2048 * 267;    // [2048,32]
  float* outLv = outMu + 2048 * 32;   // [2048,32]

  float* ws = (float*)d_ws;
  unsigned short* Ax   = (unsigned short*)(ws);             // 2048x544 bf16
  unsigned short* Axh  = (unsigned short*)(ws + 557056);    // 2048x544
  unsigned short* Axh2 = (unsigned short*)(ws + 1114112);   // 2048x544
  unsigned short* A0   = (unsigned short*)(ws + 1671168);   // 2048x320
  unsigned short* A1   = (unsigned short*)(ws + 1998848);   // 2048x288
  unsigned short* A2   = (unsigned short*)(ws + 2293760);   // 2048x288
  unsigned short* fc1t = (unsigned short*)(ws + 2588672);   // 256x544
  unsigned short* fc2t = (unsigned short*)(ws + 2658304);   // 256x544
  unsigned short* mlvt = (unsigned short*)(ws + 2727936);   // 64x544
  unsigned short* g0t  = (unsigned short*)(ws + 2745344);   // 64x320
  unsigned short* w0b  = (unsigned short*)(ws + 2755584);   // 8x256x320
  unsigned short* w1b  = (unsigned short*)(ws + 3083264);   // 8x256x288
  unsigned short* w2b  = (unsigned short*)(ws + 3378176);   // 8x267x288
  float* P  = ws + 3685760;   // 4x2048x64 fp32 partials
  float* ga = ws + 4210048;   // 2048x64
  float* gbuf = ws + 4341120; // 2048x64
  float* cf = ws + 4472192;   // 2048x8

  dim3 blk(256);
  // ---- prep (pack/convert, per-call; inputs restored each launch) ----
  prep_rows<<<2048, blk, 0, stream>>>(x, c, Ax, Axh, Axh2, A0);
  prep_weights<<<640, blk, 0, stream>>>(fc1w, fc2w, muw, lvw, g0w, fc1t, fc2t, mlvt, g0t);
  prep_wT<<<6232, blk, 0, stream>>>(w0, w1, w2, w0b, w1b, w2b);
  // ---- encoder ----
  mfma_gemm<17, false, false, true><<<dim3(32, 4, 1), blk, 0, stream>>>(
      Ax, 544, fc1t, 544, 256, fc1b, nullptr, nullptr, 0, Axh, 544, 267);
  mfma_gemm<17, false, false, true><<<dim3(32, 4, 1), blk, 0, stream>>>(
      Axh, 544, fc2t, 544, 256, fc2b, nullptr, nullptr, 0, Axh2, 544, 267);
  mfma_gemm<17, false, true, false><<<dim3(32, 1, 4), blk, 0, stream>>>(
      Axh2, 544, mlvt, 544, 64, nullptr, nullptr, P, 64, nullptr, 0, 0);
  reduce_mulv<<<512, blk, 0, stream>>>(P, mub, lvb, outMu, outLv);
  // ---- reparameterize (exact JAX threefry) ----
  z_eps_kernel<<<256, blk, 0, stream>>>(outMu, outLv, A0, A1, A2);
  // ---- gate ----
  mfma_gemm<10, false, true, false><<<dim3(32, 1, 4), blk, 0, stream>>>(
      A0, 320, g0t, 320, 64, nullptr, nullptr, P, 64, nullptr, 0, 0);
  reduce_g0<<<512, blk, 0, stream>>>(P, g0b, ga);
  linear_kernel<64, true><<<dim3(1, 64), blk, 0, stream>>>(ga, 64, nullptr, 0, g1w, g1b, gbuf, 64);
  gate_softmax_kernel<<<64, blk, 0, stream>>>(gbuf, g2w, g2b, cf);
  // ---- mixture-of-experts decoder (exact fp32 coeff folding) ----
  mfma_gemm<10, true, false, true><<<dim3(32, 4, 1), blk, 0, stream>>>(
      A0, 320, w0b, 320, 256, b0, cf, nullptr, 0, A1, 288, 32);
  mfma_gemm<9, true, false, true><<<dim3(32, 4, 1), blk, 0, stream>>>(
      A1, 288, w1b, 288, 256, b1, cf, nullptr, 0, A2, 288, 32);
  mfma_gemm<9, true, false, false><<<dim3(32, 5, 1), blk, 0, stream>>>(
      A2, 288, w2b, 288, 267, b2, cf, outY, 267, nullptr, 0, 0);
}

// Round 3
// 222.695 us; speedup vs baseline: 4.8948x; 1.3566x over previous
//
#include <hip/hip_runtime.h>
#include <math.h>
#include <stdint.h>

#define DI __device__ __forceinline__

typedef __attribute__((ext_vector_type(8))) short bf16x8;
typedef __attribute__((ext_vector_type(4))) float f32x4;
typedef __attribute__((ext_vector_type(4))) int i32x4;

DI float elu_f(float v) { return v > 0.f ? v : expm1f(v); }

DI unsigned short f2bf(float f) {  // fp32 -> bf16 RNE
  uint32_t u = __float_as_uint(f);
  return (unsigned short)((u + 0x7FFFu + ((u >> 16) & 1u)) >> 16);
}

// ------------------------------------------------ threefry2x32 (JAX, 20 rounds)
DI void threefry2x32(uint32_t k0, uint32_t k1, uint32_t& x0, uint32_t& x1) {
  uint32_t ks0 = k0, ks1 = k1, ks2 = k0 ^ k1 ^ 0x1BD11BDAu;
  x0 += ks0; x1 += ks1;
#define TFR(r) { x0 += x1; x1 = (x1 << r) | (x1 >> (32 - r)); x1 ^= x0; }
  TFR(13) TFR(15) TFR(26) TFR(6)   x0 += ks1; x1 += ks2 + 1u;
  TFR(17) TFR(29) TFR(16) TFR(24)  x0 += ks2; x1 += ks0 + 2u;
  TFR(13) TFR(15) TFR(26) TFR(6)   x0 += ks0; x1 += ks1 + 3u;
  TFR(17) TFR(29) TFR(16) TFR(24)  x0 += ks1; x1 += ks2 + 4u;
  TFR(13) TFR(15) TFR(26) TFR(6)   x0 += ks2; x1 += ks0 + 5u;
#undef TFR
}

// Giles erfinv, f32 (rel err ~1e-6 — far below bf16 quantum of z)
DI float erfinv_f(float x) {
  float w = -logf((1.0f - x) * (1.0f + x));
  float p;
  if (w < 5.0f) {
    w -= 2.5f;
    p = 2.81022636e-08f;
    p = fmaf(p, w, 3.43273939e-07f);
    p = fmaf(p, w, -3.5233877e-06f);
    p = fmaf(p, w, -4.39150654e-06f);
    p = fmaf(p, w, 0.00021858087f);
    p = fmaf(p, w, -0.00125372503f);
    p = fmaf(p, w, -0.00417768164f);
    p = fmaf(p, w, 0.246640727f);
    p = fmaf(p, w, 1.50140941f);
  } else {
    w = sqrtf(w) - 3.0f;
    p = -0.000200214257f;
    p = fmaf(p, w, 0.000100950558f);
    p = fmaf(p, w, 0.00134934322f);
    p = fmaf(p, w, -0.00367342844f);
    p = fmaf(p, w, 0.00573950773f);
    p = fmaf(p, w, -0.0076224613f);
    p = fmaf(p, w, 0.00943887047f);
    p = fmaf(p, w, 1.00167406f);
    p = fmaf(p, w, 2.83297682f);
  }
  return p * x;
}

// ------------------------------------------------ prep: everything packed/converted in ONE dispatch
// blocks [0,512): input rows (4 rows each)   [512,1152): row-major weights
// 1152: g1w->bf16                            [1153,1673): expert W tile-transposes
__global__ __launch_bounds__(256)
void prep_kernel(const float* __restrict__ x, const float* __restrict__ c,
                 const float* __restrict__ fc1w, const float* __restrict__ fc2w,
                 const float* __restrict__ muw, const float* __restrict__ lvw,
                 const float* __restrict__ g0w, const float* __restrict__ g1w,
                 const float* __restrict__ w0, const float* __restrict__ w1,
                 const float* __restrict__ w2,
                 unsigned short* __restrict__ Ax, unsigned short* __restrict__ Axh,
                 unsigned short* __restrict__ Axh2, unsigned short* __restrict__ A0,
                 unsigned short* __restrict__ fc1t, unsigned short* __restrict__ fc2t,
                 unsigned short* __restrict__ mlvt, unsigned short* __restrict__ g0t,
                 unsigned short* __restrict__ g1t,
                 unsigned short* __restrict__ w0b, unsigned short* __restrict__ w1b,
                 unsigned short* __restrict__ w2b) {
  const int bb = blockIdx.x, tid = threadIdx.x;
  if (bb < 512) {
    for (int rr = 0; rr < 4; rr++) {
      int b = bb * 4 + rr;
      const float* xr = x + (size_t)b * 267;
      const float* cr = c + (size_t)b * 267;
      unsigned short* axr = Ax + (size_t)b * 544;
      for (int k = tid; k < 544; k += 256) {
        float v = (k < 267) ? xr[k] : ((k < 534) ? cr[k - 267] : 0.f);
        axr[k] = f2bf(v);
      }
      unsigned short* ahr = Axh + (size_t)b * 544;
      unsigned short* ah2 = Axh2 + (size_t)b * 544;
      for (int k = tid; k < 267; k += 256) { unsigned short v = f2bf(xr[k]); ahr[k] = v; ah2[k] = v; }
      for (int k = 523 + tid; k < 544; k += 256) { ahr[k] = 0; ah2[k] = 0; }
      unsigned short* a0r = A0 + (size_t)b * 320;
      for (int k = tid; k < 288; k += 256)
        a0r[32 + k] = (k < 267) ? f2bf(cr[k]) : (unsigned short)0;
    }
  } else if (bb < 1152) {
    int r = bb - 512;
    const float* src; unsigned short* dst; int Ks, Kp2;
    if (r < 256)      { src = fc1w + (size_t)r * 534; dst = fc1t + (size_t)r * 544; Ks = 534; Kp2 = 544; }
    else if (r < 512) { int n = r - 256; src = fc2w + (size_t)n * 523; dst = fc2t + (size_t)n * 544; Ks = 523; Kp2 = 544; }
    else if (r < 576) { int n = r - 512; src = (n < 32) ? (muw + (size_t)n * 523) : (lvw + (size_t)(n - 32) * 523);
                        dst = mlvt + (size_t)n * 544; Ks = 523; Kp2 = 544; }
    else              { int n = r - 576; src = g0w + (size_t)n * 299; dst = g0t + (size_t)n * 320; Ks = 299; Kp2 = 320; }
    for (int k = tid; k < Kp2; k += 256) dst[k] = (k < Ks) ? f2bf(src[k]) : (unsigned short)0;
  } else if (bb == 1152) {
    for (int k = tid; k < 4096; k += 256) g1t[k] = f2bf(g1w[k]);
  } else {
    // expert transpose: read 64x64 tile coalesced, transpose in LDS, write coalesced
    int t = bb - 1153;
    const float* W; unsigned short* D; int K, N2, Kp2, ldW, e, kt, nt;
    if (t < 160)      { e = t / 20;  int lt = t % 20;  kt = lt / 4; nt = lt % 4; W = w0; D = w0b; K = 299; N2 = 256; Kp2 = 320; ldW = 256; }
    else if (t < 320) { int u = t - 160; e = u / 20; int lt = u % 20; kt = lt / 4; nt = lt % 4; W = w1; D = w1b; K = 288; N2 = 256; Kp2 = 288; ldW = 256; }
    else              { int u = t - 320; e = u / 25; int lt = u % 25; kt = lt / 5; nt = lt % 5; W = w2; D = w2b; K = 288; N2 = 267; Kp2 = 288; ldW = 267; }
    __shared__ unsigned short T[64][72];
    const int k0 = kt * 64, n0 = nt * 64;
    const float* We = W + (size_t)e * K * ldW;
    const int jj = tid & 63, ii0 = tid >> 6;
#pragma unroll
    for (int p = 0; p < 16; p++) {
      int i = ii0 + p * 4;
      int gk = k0 + i, gn = n0 + jj;
      float v = (gk < K && gn < N2) ? We[(size_t)gk * ldW + gn] : 0.f;
      T[jj][i] = f2bf(v);
    }
    __syncthreads();
    int j = tid >> 2, chb = tid & 3;
    int gn = n0 + j;
    if (gn < N2) {
      unsigned short* drow = D + ((size_t)e * N2 + gn) * Kp2 + k0;
#pragma unroll
      for (int s = 0; s < 2; s++) {
        int ch = chb + s * 4;
        if (k0 + ch * 8 < Kp2) {
          i32x4 v = *(i32x4*)(&T[j][ch * 8]);
          *(i32x4*)(drow + ch * 8) = v;
        }
      }
    }
  }
}

// ------------------------------------------------ encoder GEMM: chunked dbuf, shared A+W
// C(bf16) = ELU(A[2048x544] @ Bt^T + bias); Bt [N][544]; tile 64x64, 256 thr.
__global__ __launch_bounds__(256)
void enc_gemm(const unsigned short* __restrict__ A,
              const unsigned short* __restrict__ Bt,
              const float* __restrict__ bias,
              unsigned short* __restrict__ Cb, int ldcb, int cb_off) {
  constexpr int KT = 17, CH = 3, NCH = 6, LC = 104;  // 3*32+8 pad -> 2-way banks
  __shared__ unsigned short Ac[2][64 * LC];
  __shared__ unsigned short Wc[2][64 * LC];
  __shared__ float bias_s[64];
  const int tid = threadIdx.x;
  const int m0 = blockIdx.x * 64, n0 = blockIdx.y * 64;
  const int lane = tid & 63, wid = tid >> 6, q = lane >> 4, l16 = lane & 15;
  const int wm = (wid >> 1) * 32, wn = (wid & 1) * 32;
  if (tid < 64) bias_s[tid] = bias[n0 + tid];
  i32x4 ra[3], rw[3];
  auto loadC = [&](int p) {
#pragma unroll
    for (int s = 0; s < 3; s++) {
      int idx = tid + s * 256;
      int row = idx / 12, ch = idx % 12;
      ra[s] = *(const i32x4*)(A + (size_t)(m0 + row) * 544 + p * 96 + ch * 8);
      rw[s] = *(const i32x4*)(Bt + (size_t)(n0 + row) * 544 + p * 96 + ch * 8);
    }
  };
  auto storeC = [&](int p) {
    int buf = p & 1;
#pragma unroll
    for (int s = 0; s < 3; s++) {
      int idx = tid + s * 256;
      int row = idx / 12, ch = idx % 12;
      *(i32x4*)(&Ac[buf][row * LC + ch * 8]) = ra[s];
      *(i32x4*)(&Wc[buf][row * LC + ch * 8]) = rw[s];
    }
  };
  loadC(0); storeC(0); __syncthreads();
  f32x4 acc[2][2] = {};
  for (int p = 0; p < NCH; p++) {
    if (p + 1 < NCH) loadC(p + 1);
    int buf = p & 1;
#pragma unroll
    for (int tl = 0; tl < CH; tl++) {
      int tau = p * CH + tl;
      if (tau >= KT) break;
      bf16x8 af[2], bw[2];
#pragma unroll
      for (int mi = 0; mi < 2; mi++)
        af[mi] = *(const bf16x8*)(&Ac[buf][(wm + mi * 16 + l16) * LC + tl * 32 + q * 8]);
#pragma unroll
      for (int ni = 0; ni < 2; ni++)
        bw[ni] = *(const bf16x8*)(&Wc[buf][(wn + ni * 16 + l16) * LC + tl * 32 + q * 8]);
#pragma unroll
      for (int mi = 0; mi < 2; mi++)
#pragma unroll
        for (int ni = 0; ni < 2; ni++)
          acc[mi][ni] = __builtin_amdgcn_mfma_f32_16x16x32_bf16(af[mi], bw[ni], acc[mi][ni], 0, 0, 0);
    }
    if (p + 1 < NCH) storeC(p + 1);
    __syncthreads();
  }
#pragma unroll
  for (int mi = 0; mi < 2; mi++)
#pragma unroll
    for (int r = 0; r < 4; r++) {
      int row = m0 + wm + mi * 16 + q * 4 + r;
#pragma unroll
      for (int ni = 0; ni < 2; ni++) {
        int cl = wn + ni * 16 + l16;
        float v = elu_f(acc[mi][ni][r] + bias_s[cl]);
        Cb[(size_t)row * ldcb + cb_off + n0 + cl] = f2bf(v);
      }
    }
}

// ------------------------------------------------ mu/lv GEMM + reparameterize (fused)
__global__ __launch_bounds__(256)
void mulv_z_kernel(const unsigned short* __restrict__ A,   // Axh2 [2048][544]
                   const unsigned short* __restrict__ Bt,  // mlvt [64][544]
                   const float* __restrict__ mub, const float* __restrict__ lvb,
                   float* __restrict__ outMu, float* __restrict__ outLv,
                   unsigned short* __restrict__ A0z, unsigned short* __restrict__ A1z,
                   unsigned short* __restrict__ A2z) {
  constexpr int KT = 17, CH = 3, NCH = 6, LC = 104;
  __shared__ unsigned short Ac[2][64 * LC];
  __shared__ unsigned short Wc[2][64 * LC];
  __shared__ float bias_s[64];
  const int tid = threadIdx.x;
  const int m0 = blockIdx.x * 64;
  const int lane = tid & 63, wid = tid >> 6, q = lane >> 4, l16 = lane & 15;
  const int wm = (wid >> 1) * 32, wn = (wid & 1) * 32;
  if (tid < 64) bias_s[tid] = (tid < 32) ? mub[tid] : lvb[tid - 32];
  i32x4 ra[3], rw[3];
  auto loadC = [&](int p) {
#pragma unroll
    for (int s = 0; s < 3; s++) {
      int idx = tid + s * 256;
      int row = idx / 12, ch = idx % 12;
      ra[s] = *(const i32x4*)(A + (size_t)(m0 + row) * 544 + p * 96 + ch * 8);
      rw[s] = *(const i32x4*)(Bt + (size_t)row * 544 + p * 96 + ch * 8);
    }
  };
  auto storeC = [&](int p) {
    int buf = p & 1;
#pragma unroll
    for (int s = 0; s < 3; s++) {
      int idx = tid + s * 256;
      int row = idx / 12, ch = idx % 12;
      *(i32x4*)(&Ac[buf][row * LC + ch * 8]) = ra[s];
      *(i32x4*)(&Wc[buf][row * LC + ch * 8]) = rw[s];
    }
  };
  loadC(0); storeC(0); __syncthreads();
  f32x4 acc[2][2] = {};
  for (int p = 0; p < NCH; p++) {
    if (p + 1 < NCH) loadC(p + 1);
    int buf = p & 1;
#pragma unroll
    for (int tl = 0; tl < CH; tl++) {
      int tau = p * CH + tl;
      if (tau >= KT) break;
      bf16x8 af[2], bw[2];
#pragma unroll
      for (int mi = 0; mi < 2; mi++)
        af[mi] = *(const bf16x8*)(&Ac[buf][(wm + mi * 16 + l16) * LC + tl * 32 + q * 8]);
#pragma unroll
      for (int ni = 0; ni < 2; ni++)
        bw[ni] = *(const bf16x8*)(&Wc[buf][(wn + ni * 16 + l16) * LC + tl * 32 + q * 8]);
#pragma unroll
      for (int mi = 0; mi < 2; mi++)
#pragma unroll
        for (int ni = 0; ni < 2; ni++)
          acc[mi][ni] = __builtin_amdgcn_mfma_f32_16x16x32_bf16(af[mi], bw[ni], acc[mi][ni], 0, 0, 0);
    }
    if (p + 1 < NCH) storeC(p + 1);
    __syncthreads();
  }
  // overlay mlvS (64x65 f32 = 16.6KB) onto chunk buffers (dead, post-barrier)
  float* mlvS = (float*)&Ac[0][0];
#pragma unroll
  for (int mi = 0; mi < 2; mi++)
#pragma unroll
    for (int r = 0; r < 4; r++) {
      int row = wm + mi * 16 + q * 4 + r;
#pragma unroll
      for (int ni = 0; ni < 2; ni++) {
        int cl = wn + ni * 16 + l16;
        mlvS[row * 65 + cl] = acc[mi][ni][r] + bias_s[cl];
      }
    }
  __syncthreads();
  // z = mu + eps*exp(0.5*lv), eps = exact JAX threefry-normal
  const int m = tid >> 2, j0 = (tid & 3) * 8;
  const int R = m0 + m;
#pragma unroll
  for (int jj = 0; jj < 8; jj++) {
    int j = j0 + jj;
    float mu = mlvS[m * 65 + j], lvv = mlvS[m * 65 + j + 32];
    uint32_t x0 = 0u, x1 = (uint32_t)(R * 32 + j);
    threefry2x32(0u, 42u, x0, x1);
    uint32_t bits = x0 ^ x1;
    float f = __uint_as_float((bits >> 9) | 0x3F800000u) - 1.0f;
    const float lo = -0.99999994039535522461f;
    float u = fmaf(f, 2.0f, lo);
    u = fmaxf(u, lo);
    float eps = 1.41421356237f * erfinv_f(u);
    float z = fmaf(eps, expf(0.5f * lvv), mu);
    outMu[(size_t)R * 32 + j] = mu;
    outLv[(size_t)R * 32 + j] = lvv;
    unsigned short zb = f2bf(z);
    A0z[(size_t)R * 320 + j] = zb;
    A1z[(size_t)R * 288 + j] = zb;
    A2z[(size_t)R * 288 + j] = zb;
  }
}

// ------------------------------------------------ fused gate: g0 MFMA -> g1 MFMA -> g2 -> softmax
__global__ __launch_bounds__(256)
void gate_kernel(const unsigned short* __restrict__ A0,   // [2048][320]
                 const unsigned short* __restrict__ g0t,  // [64][320]
                 const unsigned short* __restrict__ g1t,  // [64][64]
                 const float* __restrict__ g0b, const float* __restrict__ g1b,
                 const float* __restrict__ g2w, const float* __restrict__ g2b,
                 float* __restrict__ cf) {
  __shared__ __align__(16) unsigned char SM[61056];
  unsigned short* A0p  = (unsigned short*)SM;             // [64][328]  41984
  unsigned short* Wp   = (unsigned short*)(SM + 41984);   // 4*2*16*72  18432
  float* g0b_s = (float*)(SM + 60416);
  float* g1b_s = (float*)(SM + 60672);
  float* g2b_s = (float*)(SM + 60928);
  // phase-2 overlays (A0p/Wp dead after barriers)
  unsigned short* gaB  = (unsigned short*)SM;             // [64][72]
  unsigned short* g1B  = (unsigned short*)(SM + 9216);    // [64][72]
  float* gB   = (float*)(SM + 18432);                     // [64][65]
  float* g2wS = (float*)(SM + 35072);                     // [8][64]
  float* lg   = (float*)(SM + 37120);                     // [64][8]

  const int tid = threadIdx.x, lane = tid & 63, wid = tid >> 6;
  const int q = lane >> 4, l16 = lane & 15;
  const int m0 = blockIdx.x * 64, wn = wid * 16;
  if (tid < 64) g0b_s[tid] = g0b[tid];
  else if (tid < 128) g1b_s[tid - 64] = g1b[tid - 64];
  else if (tid < 136) g2b_s[tid - 128] = g2b[tid - 128];

  unsigned short* myW = Wp + wid * 2304;  // 2*16*72
  i32x4 wreg[2];
  auto loadWc = [&](int c2) {
#pragma unroll
    for (int s = 0; s < 2; s++) {
      int idx = lane + s * 64, row = idx >> 3, ch = idx & 7;
      wreg[s] = *(const i32x4*)(g0t + (size_t)(wn + row) * 320 + c2 * 64 + ch * 8);
    }
  };
  auto storeWc = [&](int c2) {
    int buf = c2 & 1;
#pragma unroll
    for (int s = 0; s < 2; s++) {
      int idx = lane + s * 64, row = idx >> 3, ch = idx & 7;
      *(i32x4*)(myW + (buf * 16 + row) * 72 + ch * 8) = wreg[s];
    }
  };
  loadWc(0);
  for (int s = 0; s < 10; s++) {  // A0 panel 64x40 16B-chunks
    int idx = tid + s * 256, row = idx / 40, ch = idx % 40;
    i32x4 v = *(const i32x4*)(A0 + (size_t)(m0 + row) * 320 + ch * 8);
    *(i32x4*)(A0p + row * 328 + ch * 8) = v;
  }
  storeWc(0);
  __syncthreads();
  f32x4 acc[4] = {};
  for (int c2 = 0; c2 < 5; c2++) {
    if (c2 + 1 < 5) loadWc(c2 + 1);
    int buf = c2 & 1;
#pragma unroll
    for (int tl = 0; tl < 2; tl++) {
      int tau = c2 * 2 + tl;
      bf16x8 bv = *(const bf16x8*)(myW + (buf * 16 + l16) * 72 + tl * 32 + q * 8);
#pragma unroll
      for (int mi = 0; mi < 4; mi++) {
        bf16x8 av = *(const bf16x8*)(A0p + (mi * 16 + l16) * 328 + tau * 32 + q * 8);
        acc[mi] = __builtin_amdgcn_mfma_f32_16x16x32_bf16(av, bv, acc[mi], 0, 0, 0);
      }
    }
    if (c2 + 1 < 5) storeWc(c2 + 1);
  }
  __syncthreads();  // all g0 reads of A0p/Wp done
  {
    float bcol = g0b_s[wn + l16];
#pragma unroll
    for (int mi = 0; mi < 4; mi++)
#pragma unroll
      for (int r = 0; r < 4; r++)
        gaB[(mi * 16 + q * 4 + r) * 72 + wn + l16] = f2bf(elu_f(acc[mi][r] + bcol));
  }
  for (int s = 0; s < 2; s++) {  // stage g1B
    int idx = tid + s * 256, row = idx >> 3, ch = idx & 7;
    i32x4 v = *(const i32x4*)(g1t + (size_t)row * 64 + ch * 8);
    *(i32x4*)(g1B + row * 72 + ch * 8) = v;
  }
  for (int idx = tid; idx < 512; idx += 256) g2wS[idx] = g2w[idx];
  __syncthreads();
  f32x4 acc2[4] = {};
#pragma unroll
  for (int tau = 0; tau < 2; tau++) {
    bf16x8 bv = *(const bf16x8*)(g1B + (size_t)(wn + l16) * 72 + tau * 32 + q * 8);
#pragma unroll
    for (int mi = 0; mi < 4; mi++) {
      bf16x8 av = *(const bf16x8*)(gaB + (mi * 16 + l16) * 72 + tau * 32 + q * 8);
      acc2[mi] = __builtin_amdgcn_mfma_f32_16x16x32_bf16(av, bv, acc2[mi], 0, 0, 0);
    }
  }
  {
    float b1c = g1b_s[wn + l16];
#pragma unroll
    for (int mi = 0; mi < 4; mi++)
#pragma unroll
      for (int r = 0; r < 4; r++)
        gB[(mi * 16 + q * 4 + r) * 65 + wn + l16] = elu_f(acc2[mi][r] + b1c);
  }
  __syncthreads();
  {
    int r = tid >> 2, sub = tid & 3;
    float d0 = g2b_s[sub], d1 = g2b_s[sub + 4];
    for (int k = 0; k < 64; k++) {
      float gv = gB[r * 65 + k];
      d0 = fmaf(gv, g2wS[sub * 64 + k], d0);
      d1 = fmaf(gv, g2wS[(sub + 4) * 64 + k], d1);
    }
    lg[r * 8 + sub] = d0;
    lg[r * 8 + sub + 4] = d1;
  }
  __syncthreads();
  if (tid < 64) {
    float mx = lg[tid * 8];
#pragma unroll
    for (int e = 1; e < 8; e++) mx = fmaxf(mx, lg[tid * 8 + e]);
    float s = 0.f, ex[8];
#pragma unroll
    for (int e = 0; e < 8; e++) { ex[e] = expf(lg[tid * 8 + e] - mx); s += ex[e]; }
    float inv = 1.f / s;
#pragma unroll
    for (int e = 0; e < 8; e++) cf[(size_t)(m0 + tid) * 8 + e] = ex[e] * inv;
  }
}

// ------------------------------------------------ MoE layer: A full-resident, wave-private W, no inner barriers
template <int KT, int ELU>
__global__ __launch_bounds__(256)
void moe_kernel(const unsigned short* __restrict__ A, int lda,  // [2048][KT*32]
                const unsigned short* __restrict__ Wt, int N,   // [8][N][KT*32]
                const float* __restrict__ bE,                   // [8][N]
                const float* __restrict__ cfp,                  // [2048][8]
                unsigned short* __restrict__ Cb, int ldcb,      // next-layer A (+32) or null
                float* __restrict__ Cf) {                       // outY f32 or null
  constexpr int Kp = KT * 32, LKA = Kp + 8, NCH = (KT + 1) / 2, CPR = Kp / 8;
  __shared__ unsigned short As[64 * LKA];
  __shared__ unsigned short Wp[4 * 2 * 16 * 72];
  __shared__ float bias_s[512];
  __shared__ float cfs[512];
  const int tid = threadIdx.x, lane = tid & 63, wid = tid >> 6;
  const int q = lane >> 4, l16 = lane & 15;
  const int m0 = blockIdx.x * 64, n0 = blockIdx.y * 64, wn = wid * 16;
  unsigned short* myW = Wp + wid * 2304;
  i32x4 wreg[2];
  auto loadWc = [&](int e, int c2) {
#pragma unroll
    for (int s = 0; s < 2; s++) {
      int idx = lane + s * 64, row = idx >> 3, ch = idx & 7;
      int gn = n0 + wn + row;
      if (gn < N)
        wreg[s] = *(const i32x4*)(Wt + ((size_t)e * N + gn) * Kp + c2 * 64 + ch * 8);
      else { wreg[s][0] = 0; wreg[s][1] = 0; wreg[s][2] = 0; wreg[s][3] = 0; }
    }
  };
  auto storeWc = [&](int c2) {
    int buf = c2 & 1;
#pragma unroll
    for (int s = 0; s < 2; s++) {
      int idx = lane + s * 64, row = idx >> 3, ch = idx & 7;
      *(i32x4*)(myW + (buf * 16 + row) * 72 + ch * 8) = wreg[s];
    }
  };
  loadWc(0, 0);
  for (int idx = tid; idx < 64 * CPR; idx += 256) {
    int row = idx / CPR, ch = idx % CPR;
    i32x4 v = *(const i32x4*)(A + (size_t)(m0 + row) * lda + ch * 8);
    *(i32x4*)(As + row * LKA + ch * 8) = v;
  }
  for (int idx = tid; idx < 512; idx += 256) {
    int e = idx >> 6, col = idx & 63;
    bias_s[idx] = (n0 + col < N) ? bE[(size_t)e * N + n0 + col] : 0.f;
  }
  for (int idx = tid; idx < 512; idx += 256)
    cfs[idx] = cfp[(size_t)(m0 + (idx >> 3)) * 8 + (idx & 7)];
  storeWc(0);
  __syncthreads();  // the only barrier

  f32x4 acc[4] = {}, accF[4] = {};
  const int total = 8 * NCH;
  for (int g = 0; g < total; g++) {
    int e = g / NCH, c2 = g % NCH;
    if (g + 1 < total) loadWc((g + 1) / NCH, (g + 1) % NCH);
    int buf = c2 & 1;
#pragma unroll
    for (int tl = 0; tl < 2; tl++) {
      int tau = c2 * 2 + tl;
      if (tau >= KT) break;
      bf16x8 bv = *(const bf16x8*)(myW + (buf * 16 + l16) * 72 + tl * 32 + q * 8);
#pragma unroll
      for (int mi = 0; mi < 4; mi++) {
        bf16x8 av = *(const bf16x8*)(As + (mi * 16 + l16) * LKA + tau * 32 + q * 8);
        acc[mi] = __builtin_amdgcn_mfma_f32_16x16x32_bf16(av, bv, acc[mi], 0, 0, 0);
      }
    }
    if (g + 1 < total) storeWc((g + 1) % NCH);
    if (c2 == NCH - 1) {  // expert boundary: exact fp32 fold
      float bv2 = bias_s[e * 64 + wn + l16];
#pragma unroll
      for (int mi = 0; mi < 4; mi++)
#pragma unroll
        for (int r = 0; r < 4; r++) {
          float ce = cfs[(mi * 16 + q * 4 + r) * 8 + e];
          accF[mi][r] += ce * (acc[mi][r] + bv2);
          acc[mi][r] = 0.f;
        }
    }
  }
  const int col = n0 + wn + l16;
  if (col < N) {
#pragma unroll
    for (int mi = 0; mi < 4; mi++)
#pragma unroll
      for (int r = 0; r < 4; r++) {
        int row = m0 + mi * 16 + q * 4 + r;
        float v = accF[mi][r];
        if (ELU) v = elu_f(v);
        if (Cb) Cb[(size_t)row * ldcb + 32 + col] = f2bf(v);
        if (Cf) Cf[(size_t)row * 267 + col] = v;
      }
  }
}

// ------------------------------------------------ launch
extern "C" void kernel_launch(void* const* d_in, const int* in_sizes, int n_in,
                              void* d_out, int out_size, void* d_ws, size_t ws_size,
                              hipStream_t stream) {
  (void)in_sizes; (void)n_in; (void)out_size; (void)ws_size;
  const float* x    = (const float*)d_in[0];
  const float* c    = (const float*)d_in[1];
  const float* fc1w = (const float*)d_in[2];
  const float* fc1b = (const float*)d_in[3];
  const float* fc2w = (const float*)d_in[4];
  const float* fc2b = (const float*)d_in[5];
  const float* muw  = (const float*)d_in[6];
  const float* mub  = (const float*)d_in[7];
  const float* lvw  = (const float*)d_in[8];
  const float* lvb  = (const float*)d_in[9];
  const float* g0w  = (const float*)d_in[10];
  const float* g0b  = (const float*)d_in[11];
  const float* g1w  = (const float*)d_in[12];
  const float* g1b  = (const float*)d_in[13];
  const float* g2w  = (const float*)d_in[14];
  const float* g2b  = (const float*)d_in[15];
  const float* w0   = (const float*)d_in[16];
  const float* b0   = (const float*)d_in[17];
  const float* w1   = (const float*)d_in[18];
  const float* b1   = (const float*)d_in[19];
  const float* w2   = (const float*)d_in[20];
  const float* b2   = (const float*)d_in[21];

  float* out   = (float*)d_out;
  float* outY  = out;
  float* outMu = out + 2048 * 267;
  float* outLv = outMu + 2048 * 32;

  float* ws = (float*)d_ws;
  unsigned short* Ax   = (unsigned short*)(ws);
  unsigned short* Axh  = (unsigned short*)(ws + 557056);
  unsigned short* Axh2 = (unsigned short*)(ws + 1114112);
  unsigned short* A0   = (unsigned short*)(ws + 1671168);
  unsigned short* A1   = (unsigned short*)(ws + 1998848);
  unsigned short* A2   = (unsigned short*)(ws + 2293760);
  unsigned short* fc1t = (unsigned short*)(ws + 2588672);
  unsigned short* fc2t = (unsigned short*)(ws + 2658304);
  unsigned short* mlvt = (unsigned short*)(ws + 2727936);
  unsigned short* g0t  = (unsigned short*)(ws + 2745344);
  unsigned short* g1t  = (unsigned short*)(ws + 2755584);
  unsigned short* w0b  = (unsigned short*)(ws + 2757632);
  unsigned short* w1b  = (unsigned short*)(ws + 3085312);
  unsigned short* w2b  = (unsigned short*)(ws + 3380224);
  float* cf            = ws + 3687808;

  dim3 blk(256);
  prep_kernel<<<1673, blk, 0, stream>>>(x, c, fc1w, fc2w, muw, lvw, g0w, g1w, w0, w1, w2,
                                        Ax, Axh, Axh2, A0, fc1t, fc2t, mlvt, g0t, g1t,
                                        w0b, w1b, w2b);
  enc_gemm<<<dim3(32, 4), blk, 0, stream>>>(Ax, fc1t, fc1b, Axh, 544, 267);
  enc_gemm<<<dim3(32, 4), blk, 0, stream>>>(Axh, fc2t, fc2b, Axh2, 544, 267);
  mulv_z_kernel<<<32, blk, 0, stream>>>(Axh2, mlvt, mub, lvb, outMu, outLv, A0, A1, A2);
  gate_kernel<<<32, blk, 0, stream>>>(A0, g0t, g1t, g0b, g1b, g2w, g2b, cf);
  moe_kernel<10, 1><<<dim3(32, 4), blk, 0, stream>>>(A0, 320, w0b, 256, b0, cf, A1, 288, nullptr);
  moe_kernel<9, 1><<<dim3(32, 4), blk, 0, stream>>>(A1, 288, w1b, 256, b1, cf, A2, 288, nullptr);
  moe_kernel<9, 0><<<dim3(32, 5), blk, 0, stream>>>(A2, 288, w2b, 267, b2, cf, nullptr, 0, outY);
}